// Round 7
// baseline (472.970 us; speedup 1.0000x reference)
//
#include <hip/hip_runtime.h>

// CrossAttention decode, algebraically collapsed (all fp32):
//   q[b,h,:]   = ((x1@We1+be1)@Wq+bq) head-sliced
//   u[b,h,c]   = sum_d WkT[h*64+d,c]*q[b,h,d]
//   w[b,h,i]   = sum_c u[b,h,c]*We2t[c,i]          (K-proj folded)
//   score[b,h,s] = x2[b,s,:].w[b,h,:]              (K-bias cancels in softmax)
//   a = softmax(score/8)
//   g[b,h,i]   = sum_s a[b,h,s]*x3[b,s,i]
//   G2[b,h,c]  = g@We2 + be2;  av = G2@Wv_h + bv;  out = av@Wo + bo
// k_attn fuses scores+softmax+PV flash-style. R6 lesson: at NCH=32 (512
// blocks = 2 blocks/CU) k_attn was latency-bound (126us, VALU 23%, HBM 16%,
// occ 21%) — barriers + exp chains unhidden at 2 waves/SIMD. NCH=64 gives
// 1024 blocks = 4 blocks/CU (LDS 38.4KB and VGPR 128 both allow exactly 4).
// Other lessons: no per-element global atomics on hot paths (R4 = 134MB
// RMW); stride-33 float4 LDS tiles (conflict-free); harness reset (~170us:
// 537MB poison fill + d_in restore) is fixed overhead in the window.

#define DIN 512
#define DD  1024
#define NH  16
#define HD  64
#define BB  16
#define SS  4096
#define NCH 64   // s-chunks; 64 rows per block

__device__ __forceinline__ int wave_id() {
    return __builtin_amdgcn_readfirstlane((int)(threadIdx.x >> 6));
}

__device__ __forceinline__ void tile_transpose(const float* __restrict__ in,
                                               float* __restrict__ out,
                                               int R, int C, int rblk, int cblk) {
    __shared__ float tl[32][33];
    const int tx = threadIdx.x & 31, ty = threadIdx.x >> 5;  // ty 0..7
    const int c0 = cblk * 32, r0 = rblk * 32;
#pragma unroll
    for (int k = 0; k < 4; ++k)
        tl[ty + k * 8][tx] = in[(size_t)(r0 + ty + k * 8) * C + c0 + tx];
    __syncthreads();
#pragma unroll
    for (int k = 0; k < 4; ++k)
        out[(size_t)(c0 + ty + k * 8) * R + r0 + tx] = tl[tx][ty + k * 8];
}

// One fused prep dispatch: We2/Wk transposes + bias init of atomic targets.
__global__ __launch_bounds__(256) void k_prep(const float* __restrict__ We2,
                                              const float* __restrict__ Wk,
                                              const float* __restrict__ be1,
                                              const float* __restrict__ bq,
                                              const float* __restrict__ bv,
                                              const float* __restrict__ bo,
                                              float* __restrict__ We2t,
                                              float* __restrict__ WkT,
                                              float* __restrict__ x1e,
                                              float* __restrict__ qb,
                                              float* __restrict__ av,
                                              float* __restrict__ out) {
    const int bx = blockIdx.x;
    if (bx < 512) {
        tile_transpose(We2, We2t, DIN, DD, bx >> 5, bx & 31);
    } else if (bx < 1536) {
        const int lb = bx - 512;
        tile_transpose(Wk, WkT, DD, DD, lb >> 5, lb & 31);
    } else {
        const int b = bx - 1536;
#pragma unroll
        for (int k = 0; k < 4; ++k) {
            const int c = k * 256 + threadIdx.x;
            x1e[(size_t)b * DD + c] = be1[c];
            qb[(size_t)b * DD + c]  = bq[c];
            av[(size_t)b * DD + c]  = bv[c];
            out[(size_t)b * DD + c] = bo[c];
        }
    }
}

// out[r][c] (+)= sum_i in[r][i]*W[i][c] for 16 rows. grid (N/64, R/16, KS).
template <int K, int N, int KS, bool HASB>
__global__ __launch_bounds__(256) void k_bmv2(const float* __restrict__ in,
                                              const float* __restrict__ W,
                                              const float* __restrict__ bias,
                                              float* __restrict__ out) {
    const int l = threadIdx.x & 63;
    const int c = blockIdx.x * 64 + l;
    const int wv = wave_id();
    constexpr int KCH = K / KS;
    constexpr int SUB = KCH / 4;
    const float* inb = in + (size_t)blockIdx.y * 16 * K;  // uniform -> s_load
    float acc[16];
#pragma unroll
    for (int r = 0; r < 16; ++r) acc[r] = 0.f;
    const int i0 = blockIdx.z * KCH + wv * SUB;
#pragma unroll 4
    for (int i = i0; i < i0 + SUB; ++i) {
        const float wval = W[(size_t)i * N + c];  // coalesced 256B/wave
#pragma unroll
        for (int r = 0; r < 16; ++r) acc[r] += inb[(size_t)r * K + i] * wval;
    }
    __shared__ float red[4][16][64];
#pragma unroll
    for (int r = 0; r < 16; ++r) red[wv][r][l] = acc[r];
    __syncthreads();
#pragma unroll
    for (int k = 0; k < 4; ++k) {
        const int r = wv + k * 4;
        float v = red[0][r][l] + red[1][r][l] + red[2][r][l] + red[3][r][l];
        float* dst = out + ((size_t)blockIdx.y * 16 + r) * N + c;
        if (KS == 1) {
            if (HASB) v += bias[c];
            *dst = v;
        } else {
            atomicAdd(dst, v);
        }
    }
}

// u[b*16+h][c] = sum_d q[b][h*64+d]*WkT[h*64+d][c].  grid (1024/64, 16 h).
__global__ __launch_bounds__(256) void k_u2(const float* __restrict__ q,
                                            const float* __restrict__ WkT,
                                            float* __restrict__ u) {
    const int h = blockIdx.y;
    const int l = threadIdx.x & 63;
    const int c = blockIdx.x * 64 + l;
    const int wv = wave_id();
    float acc[16];
#pragma unroll
    for (int bb = 0; bb < 16; ++bb) acc[bb] = 0.f;
#pragma unroll 4
    for (int dk = 0; dk < 16; ++dk) {
        const int d = wv * 16 + dk;
        const float wval = WkT[(size_t)(h * HD + d) * DD + c];  // coalesced
#pragma unroll
        for (int bb = 0; bb < 16; ++bb)
            acc[bb] += q[(size_t)bb * DD + h * HD + d] * wval;  // s_load
    }
    __shared__ float red[4][16][64];
#pragma unroll
    for (int bb = 0; bb < 16; ++bb) red[wv][bb][l] = acc[bb];
    __syncthreads();
#pragma unroll
    for (int k = 0; k < 4; ++k) {
        const int bb = wv + k * 4;
        float v = red[0][bb][l] + red[1][bb][l] + red[2][bb][l] + red[3][bb][l];
        u[((size_t)bb * NH + h) * DD + c] = v;
    }
}

// Fused scores+softmax+PV: grid (NCH, 16 b), block 256 (4 waves), 64 s-rows
// per block. Phase A: scores (wave = 4 heads, lane = s-row, x2 staged in
// stride-33 LDS), parked in scb. Phase B: wave wv owns s-rows wv*16..+16 for
// ALL 16 heads, lane owns 8 i-cols; softmax-weighted x3 rows into acc[16][8].
// Block combine rescales waves to a common max; writes gp + (m,l) per head.
__global__ __launch_bounds__(256) void k_attn(const float* __restrict__ x2,
                                              const float* __restrict__ x3,
                                              const float* __restrict__ w,
                                              float* __restrict__ gp,
                                              float* __restrict__ mls) {
    __shared__ __align__(16) char smem[64 * 33 * 16 + 16 * 64 * 4];  // 37.9KB
    float4* tile = (float4*)smem;                    // 33.8KB (phase A)
    float*  scb  = (float*)(smem + 64 * 33 * 16);    // 4KB scores [h][s]
    float*  red  = (float*)smem;                     // 32KB (combine; tile dead)
    __shared__ float sm[4][16], sl[4][16];

    const int b = blockIdx.y, ch = blockIdx.x;
    const int l = threadIdx.x & 63;
    const int wv = wave_id();
    const int h0 = wv * 4;
    const int s0 = ch * 64;
    const float4* wp = (const float4*)(w + ((size_t)b * NH + h0) * DIN);

    // ---- phase A: scores for rows s0..s0+64 ----
    const float4* x2f = (const float4*)x2 + ((size_t)b * SS + s0) * (DIN / 4);
    float a0 = 0.f, a1 = 0.f, a2 = 0.f, a3 = 0.f;
    for (int kt = 0; kt < 4; ++kt) {
        if (kt) __syncthreads();
#pragma unroll
        for (int k = 0; k < 8; ++k) {
            const int idx = threadIdx.x + k * 256;
            const int row = idx >> 5, c4 = idx & 31;
            tile[row * 33 + c4] = x2f[row * (DIN / 4) + kt * 32 + c4];
        }
        __syncthreads();
#pragma unroll 8
        for (int c4 = 0; c4 < 32; ++c4) {
            const float4 x = tile[l * 33 + c4];
            const float4 q0 = wp[kt * 32 + c4];            // uniform
            const float4 q1 = wp[128 + kt * 32 + c4];
            const float4 q2 = wp[256 + kt * 32 + c4];
            const float4 q3 = wp[384 + kt * 32 + c4];
            a0 += x.x * q0.x + x.y * q0.y + x.z * q0.z + x.w * q0.w;
            a1 += x.x * q1.x + x.y * q1.y + x.z * q1.z + x.w * q1.w;
            a2 += x.x * q2.x + x.y * q2.y + x.z * q2.z + x.w * q2.w;
            a3 += x.x * q3.x + x.y * q3.y + x.z * q3.z + x.w * q3.w;
        }
    }
    scb[(h0 + 0) * 64 + l] = a0;
    scb[(h0 + 1) * 64 + l] = a1;
    scb[(h0 + 2) * 64 + l] = a2;
    scb[(h0 + 3) * 64 + l] = a3;
    __syncthreads();

    // ---- phase B: softmax + PV for rows sq..sq+16, all 16 heads ----
    const int sq = wv * 16;
    float m[16], lsum[16], acc[16][8];
#pragma unroll
    for (int h = 0; h < 16; ++h) {
        float mm = -1e30f;
#pragma unroll
        for (int j = 0; j < 16; ++j) mm = fmaxf(mm, scb[h * 64 + sq + j]);
        m[h] = mm * 0.125f;
        lsum[h] = 0.f;
#pragma unroll
        for (int j = 0; j < 8; ++j) acc[h][j] = 0.f;
    }
    for (int j = 0; j < 16; ++j) {
        const int s = s0 + sq + j;
        const float4* xr = (const float4*)(x3 + ((size_t)b * SS + s) * DIN);
        const float4 xa = xr[l];
        const float4 xb = xr[l + 64];
        const float xv[8] = {xa.x, xa.y, xa.z, xa.w, xb.x, xb.y, xb.z, xb.w};
#pragma unroll
        for (int h = 0; h < 16; ++h) {
            const float e = __expf(scb[h * 64 + sq + j] * 0.125f - m[h]);
            lsum[h] += e;
#pragma unroll
            for (int jj = 0; jj < 8; ++jj) acc[h][jj] += e * xv[jj];
        }
    }

    // ---- block combine: rescale all waves to common per-head max ----
#pragma unroll
    for (int h = 0; h < 16; ++h) sm[wv][h] = m[h];
    __syncthreads();
#pragma unroll
    for (int h = 0; h < 16; ++h) {
        const float bmh = fmaxf(fmaxf(sm[0][h], sm[1][h]), fmaxf(sm[2][h], sm[3][h]));
        const float f = __expf(m[h] - bmh);
        lsum[h] *= f;
#pragma unroll
        for (int j = 0; j < 8; ++j) acc[h][j] *= f;
    }
#pragma unroll
    for (int h = 0; h < 16; ++h) sl[wv][h] = lsum[h];

#pragma unroll
    for (int hg = 0; hg < 4; ++hg) {
        __syncthreads();
#pragma unroll
        for (int hh = 0; hh < 4; ++hh) {
            const int hs = hg * 4 + hh;
            float* dst = &red[wv * 2048 + hh * 512];
            *(float4*)(dst + l * 4) =
                make_float4(acc[hs][0], acc[hs][1], acc[hs][2], acc[hs][3]);
            *(float4*)(dst + 256 + l * 4) =
                make_float4(acc[hs][4], acc[hs][5], acc[hs][6], acc[hs][7]);
        }
        __syncthreads();
        const int idx = threadIdx.x * 8;
        const int hh = idx >> 9;
        const int i = idx & 511;
        float o[8];
#pragma unroll
        for (int j = 0; j < 8; ++j)
            o[j] = red[0 * 2048 + idx + j] + red[1 * 2048 + idx + j] +
                   red[2 * 2048 + idx + j] + red[3 * 2048 + idx + j];
        float* dstg = gp + (((size_t)(b * NCH + ch) * NH) + hg * 4 + hh) * DIN + i;
        *(float4*)dstg = make_float4(o[0], o[1], o[2], o[3]);
        *(float4*)(dstg + 4) = make_float4(o[4], o[5], o[6], o[7]);
    }
    if (threadIdx.x < 16) {
        const int h = threadIdx.x;
        const float bmh = fmaxf(fmaxf(sm[0][h], sm[1][h]), fmaxf(sm[2][h], sm[3][h]));
        const float L = sl[0][h] + sl[1][h] + sl[2][h] + sl[3][h];
        float* dst = mls + (((size_t)b * NCH + ch) * NH + h) * 2;
        dst[0] = bmh;
        dst[1] = L;
    }
}

// Flash combine: g[b*16+h][i] = sum_ch exp(m_ch-M)*gp_ch[i] / sum_ch exp(m_ch-M)*l_ch
__global__ __launch_bounds__(256) void k_greduce2(const float* __restrict__ gp,
                                                  const float* __restrict__ mls,
                                                  float* __restrict__ g) {
    const int pair = blockIdx.x;  // 256
    const int b = pair >> 4, h = pair & 15;
    float M = -1e30f;
    for (int ch = 0; ch < NCH; ++ch)
        M = fmaxf(M, mls[(((size_t)b * NCH + ch) * NH + h) * 2]);
    float fch[NCH];
    float L = 0.f;
    for (int ch = 0; ch < NCH; ++ch) {
        const float* p = mls + (((size_t)b * NCH + ch) * NH + h) * 2;
        const float f = __expf(p[0] - M);
        fch[ch] = f;
        L += f * p[1];
    }
    const float invL = 1.f / L;
#pragma unroll
    for (int kk = 0; kk < 2; ++kk) {
        const int i = kk * 256 + threadIdx.x;
        float acc = 0.f;
        for (int ch = 0; ch < NCH; ++ch)
            acc += fch[ch] * gp[((size_t)(b * NCH + ch) * NH + h) * DIN + i];
        g[(size_t)pair * DIN + i] = acc * invL;
    }
}

// av[b][h*64+l] (+)= sum_c G2[b*16+h][c]*Wv[c][h*64+l] over a 128-c chunk.
__global__ __launch_bounds__(256) void k_av_at(const float* __restrict__ G2,
                                               const float* __restrict__ Wv,
                                               float* __restrict__ av) {
    const int h = blockIdx.x;
    const int l = threadIdx.x & 63;
    const int wv = wave_id();
    const int c0 = blockIdx.y * 128 + wv * 32;
    float acc[16];
#pragma unroll
    for (int bb = 0; bb < 16; ++bb) acc[bb] = 0.f;
#pragma unroll 4
    for (int c = c0; c < c0 + 32; ++c) {
        const float wval = Wv[(size_t)c * DD + h * HD + l];  // coalesced
#pragma unroll
        for (int bb = 0; bb < 16; ++bb)
            acc[bb] += G2[((size_t)bb * NH + h) * DD + c] * wval;  // s_load
    }
    __shared__ float red[4][16][64];
#pragma unroll
    for (int bb = 0; bb < 16; ++bb) red[wv][bb][l] = acc[bb];
    __syncthreads();
#pragma unroll
    for (int k = 0; k < 4; ++k) {
        const int bb = wv + k * 4;
        float v = red[0][bb][l] + red[1][bb][l] + red[2][bb][l] + red[3][bb][l];
        atomicAdd(&av[(size_t)bb * DD + h * HD + l], v);
    }
}

extern "C" void kernel_launch(void* const* d_in, const int* in_sizes, int n_in,
                              void* d_out, int out_size, void* d_ws, size_t ws_size,
                              hipStream_t stream) {
    const float* x1  = (const float*)d_in[0];
    const float* x2  = (const float*)d_in[1];
    const float* x3  = (const float*)d_in[2];
    const float* We1 = (const float*)d_in[3];
    const float* be1 = (const float*)d_in[4];
    const float* We2 = (const float*)d_in[5];
    const float* be2 = (const float*)d_in[6];
    const float* Wq  = (const float*)d_in[7];
    const float* bq  = (const float*)d_in[8];
    const float* Wk  = (const float*)d_in[9];
    const float* bk  = (const float*)d_in[10];  // cancels in softmax (unused)
    const float* Wv  = (const float*)d_in[11];
    const float* bv  = (const float*)d_in[12];
    const float* Wo  = (const float*)d_in[13];
    const float* bo  = (const float*)d_in[14];
    (void)bk;
    float* out = (float*)d_out;

    char* ws = (char*)d_ws;
    size_t off = 0;
    auto alloc = [&](size_t bytes) -> void* {
        void* p = ws + off;
        off = (off + bytes + 255) & ~(size_t)255;
        return p;
    };
    float* We2t = (float*)alloc((size_t)DD * DIN * 4);  // [1024][512]
    float* WkT  = (float*)alloc((size_t)DD * DD * 4);   // [1024][1024]
    float* x1e  = (float*)alloc((size_t)BB * DD * 4);
    float* qb   = (float*)alloc((size_t)BB * DD * 4);
    float* u    = (float*)alloc((size_t)BB * NH * DD * 4);
    float* wv_  = (float*)alloc((size_t)BB * NH * DIN * 4);
    float* g    = (float*)alloc((size_t)BB * NH * DIN * 4);
    float* G2   = (float*)alloc((size_t)BB * NH * DD * 4);
    float* av   = (float*)alloc((size_t)BB * DD * 4);
    float* gp   = (float*)alloc((size_t)BB * NCH * NH * DIN * 4);  // 33.5MB
    float* mls  = (float*)alloc((size_t)BB * NCH * NH * 2 * 4);

    // prep: transposes + bias inits (one dispatch)
    k_prep<<<1552, 256, 0, stream>>>(We2, Wk, be1, bq, bv, bo,
                                     We2t, WkT, x1e, qb, av, out);
    // x1e += x1@We1   (K=512, KS=8 -> 128 blocks)
    k_bmv2<DIN, DD, 8, false><<<dim3(DD / 64, 1, 8), 256, 0, stream>>>(x1, We1, nullptr, x1e);
    // qb += x1e@Wq    (K=1024, KS=8 -> 128 blocks)
    k_bmv2<DD, DD, 8, false><<<dim3(DD / 64, 1, 8), 256, 0, stream>>>(x1e, Wq, nullptr, qb);
    k_u2<<<dim3(DD / 64, NH), 256, 0, stream>>>(qb, WkT, u);
    // w = u@We2t      (R=256 -> 128 blocks)
    k_bmv2<DD, DIN, 1, false><<<dim3(DIN / 64, BB * NH / 16, 1), 256, 0, stream>>>(u, We2t, nullptr, wv_);
    // fused scores + softmax + PV partials (1024 blocks = 4/CU)
    k_attn<<<dim3(NCH, BB), 256, 0, stream>>>(x2, x3, wv_, gp, mls);
    k_greduce2<<<BB * NH, 256, 0, stream>>>(gp, mls, g);
    // G2 = g@We2+be2  (R=256 -> 256 blocks)
    k_bmv2<DIN, DD, 1, true><<<dim3(DD / 64, BB * NH / 16, 1), 256, 0, stream>>>(g, We2, be2, G2);
    k_av_at<<<dim3(NH, 8), 256, 0, stream>>>(G2, Wv, av);
    // out += av@Wo    (K=1024, KS=8 -> 128 blocks)
    k_bmv2<DD, DD, 8, false><<<dim3(DD / 64, 1, 8), 256, 0, stream>>>(av, Wo, nullptr, out);
}